// Round 2
// baseline (24724.120 us; speedup 1.0000x reference)
//
// R1: fused pipeline. 5 kernels/step, tiled precompute GEMMs, no softmax pass.
#include <hip/hip_runtime.h>
#include <stdint.h>

#define BB 64
#define TT 256
#define SS 256
#define HH 1024
#define II 1024
#define H4 4096
#define H2 2048

static const size_t BTH = (size_t)BB * TT * HH;
static const size_t BTS = (size_t)BB * TT * SS;

typedef unsigned short u16;
typedef __attribute__((ext_vector_type(8))) short short8;
typedef __attribute__((ext_vector_type(4))) short short4v;
typedef __attribute__((ext_vector_type(4))) unsigned short u16x4;
typedef __attribute__((ext_vector_type(4))) float f32x4;

__device__ inline u16 f2bf(float x) {
    union { float f; uint32_t u; } v; v.f = x;
    uint32_t r = (v.u + 0x7FFFu + ((v.u >> 16) & 1u)) >> 16;
    return (u16)r;
}
__device__ inline float bf2f(u16 b) {
    union { float f; uint32_t u; } v; v.u = ((uint32_t)b) << 16;
    return v.f;
}
__device__ inline float fexp2(float x) { return __builtin_exp2f(x); }
__device__ inline float fast_tanh(float x) {
    x = fminf(fmaxf(x, -15.f), 15.f);
    float t = fexp2(2.885390081777927f * x);   // e^{2x}
    return 1.f - 2.f / (t + 1.f);
}
__device__ inline float sigmoidf_(float x) {
    x = fminf(fmaxf(x, -30.f), 30.f);
    float t = fexp2(-1.4426950408889634f * x);
    return 1.f / (1.f + t);
}

// ---------- conversions ----------
__global__ __launch_bounds__(256) void k_f2bf(const float* __restrict__ src,
                                              u16* __restrict__ dst, int n) {
    int i = blockIdx.x * 256 + threadIdx.x;
    if (i < n) dst[i] = f2bf(src[i]);
}
// input [B,T,I] fp32 -> time-major bf16 rows m=t*64+b
__global__ __launch_bounds__(256) void k_f2bf_tm(const float* __restrict__ src,
                                                 u16* __restrict__ dst) {
    size_t i = (size_t)blockIdx.x * 256 + threadIdx.x;   // B*T*I
    int c = (int)(i & (II - 1));
    int t = (int)((i / II) & (TT - 1));
    int b = (int)(i / ((size_t)TT * II));
    dst[((size_t)t * BB + b) * II + c] = f2bf(src[i]);
}

// ---------- 128x128 LDS-tiled GEMM: C[m,n]=A[m,:]·B[n,:]+bias[n], bf16 out ----
__global__ __launch_bounds__(256) void k_gemm128(const u16* __restrict__ A,
                                                 const u16* __restrict__ B,
                                                 const float* __restrict__ bias,
                                                 u16* __restrict__ C,
                                                 int N, int K) {
    __shared__ u16 As[128][40];
    __shared__ u16 Bs[128][40];
    int tid = threadIdx.x;
    int lane = tid & 63, wave = tid >> 6;
    int wm = wave >> 1, wn = wave & 1;
    int bm = blockIdx.y * 128, bn = blockIdx.x * 128;
    int r0 = tid >> 2, c0 = (tid & 3) * 8;

    f32x4 acc[4][4];
#pragma unroll
    for (int i = 0; i < 4; ++i)
#pragma unroll
        for (int j = 0; j < 4; ++j) acc[i][j] = (f32x4){0.f, 0.f, 0.f, 0.f};

    int row = (wm * 64) + (lane & 15);
    int kq = (lane >> 4) * 8;

    for (int k0 = 0; k0 < K; k0 += 32) {
        *(short8*)(&As[r0][c0])      = *(const short8*)(A + (size_t)(bm + r0) * K + k0 + c0);
        *(short8*)(&As[r0 + 64][c0]) = *(const short8*)(A + (size_t)(bm + r0 + 64) * K + k0 + c0);
        *(short8*)(&Bs[r0][c0])      = *(const short8*)(B + (size_t)(bn + r0) * K + k0 + c0);
        *(short8*)(&Bs[r0 + 64][c0]) = *(const short8*)(B + (size_t)(bn + r0 + 64) * K + k0 + c0);
        __syncthreads();
        short8 af[4], bf[4];
#pragma unroll
        for (int i = 0; i < 4; ++i) af[i] = *(const short8*)(&As[row + i * 16][kq]);
#pragma unroll
        for (int j = 0; j < 4; ++j) bf[j] = *(const short8*)(&Bs[(wn * 64) + (lane & 15) + j * 16][kq]);
#pragma unroll
        for (int i = 0; i < 4; ++i)
#pragma unroll
            for (int j = 0; j < 4; ++j)
                acc[i][j] = __builtin_amdgcn_mfma_f32_16x16x32_bf16(af[i], bf[j], acc[i][j], 0, 0, 0);
        __syncthreads();
    }
    int mbase = bm + wm * 64 + (lane >> 4) * 4;
    int nbase = bn + wn * 64 + (lane & 15);
#pragma unroll
    for (int j = 0; j < 4; ++j) {
        int n = nbase + j * 16;
        float bv = bias[n];
#pragma unroll
        for (int i = 0; i < 4; ++i) {
            int m0 = mbase + i * 16;
#pragma unroll
            for (int r = 0; r < 4; ++r)
                C[(size_t)(m0 + r) * N + n] = f2bf(acc[i][j][r] + bv);
        }
    }
}

// ---------- init ----------
__global__ __launch_bounds__(256) void k_init(const float* __restrict__ hx0,
                                              const float* __restrict__ cx0,
                                              float* __restrict__ cell,
                                              u16* __restrict__ buf1) {
    int i = blockIdx.x * 256 + threadIdx.x;  // B*H
    cell[i] = cx0[i];
    int b = i >> 10, h = i & 1023;
    buf1[b * H2 + HH + h] = f2bf(hx0[i]);    // hy(t=-1) lives in buf[1]
}

// ---------- K1: fused gates GEMM + LSTM cell ----------
// wave = 16 b-rows x 16 h-cols x 4 gates. grid 256 blocks x 64 thr.
__global__ __launch_bounds__(64) void k_gates_cell(const u16* __restrict__ hy_in,   // buf[(t+1)&1]+HH, stride H2
                                                   const u16* __restrict__ whidbf,
                                                   const u16* __restrict__ xg_t,
                                                   const float* __restrict__ b_hid,
                                                   float* __restrict__ cell,
                                                   float* __restrict__ outh_t,      // out + t*HH (h_out[b,t,:])
                                                   u16* __restrict__ hy_out,        // buf[t&1]+HH
                                                   float* __restrict__ sump) {
    int lane = threadIdx.x;
    int mt = blockIdx.x >> 6, nt = blockIdx.x & 63;
    if (blockIdx.x == 0) sump[lane] = 0.f;

    int kq = (lane >> 4) * 8;
    int arow = mt * 16 + (lane & 15);
    int brow = nt * 16 + (lane & 15);
    const u16* ap = hy_in + (size_t)arow * H2 + kq;
    const u16* bp0 = whidbf + (size_t)(0 * HH + brow) * HH + kq;
    const u16* bp1 = whidbf + (size_t)(1 * HH + brow) * HH + kq;
    const u16* bp2 = whidbf + (size_t)(2 * HH + brow) * HH + kq;
    const u16* bp3 = whidbf + (size_t)(3 * HH + brow) * HH + kq;

    f32x4 a0 = {0,0,0,0}, a1 = {0,0,0,0}, a2 = {0,0,0,0}, a3 = {0,0,0,0};
#pragma unroll 4
    for (int k = 0; k < HH; k += 32) {
        short8 av = *(const short8*)(ap + k);
        a0 = __builtin_amdgcn_mfma_f32_16x16x32_bf16(av, *(const short8*)(bp0 + k), a0, 0, 0, 0);
        a1 = __builtin_amdgcn_mfma_f32_16x16x32_bf16(av, *(const short8*)(bp1 + k), a1, 0, 0, 0);
        a2 = __builtin_amdgcn_mfma_f32_16x16x32_bf16(av, *(const short8*)(bp2 + k), a2, 0, 0, 0);
        a3 = __builtin_amdgcn_mfma_f32_16x16x32_bf16(av, *(const short8*)(bp3 + k), a3, 0, 0, 0);
    }
    int h = nt * 16 + (lane & 15);
    float bi = b_hid[h], bff = b_hid[HH + h], bg = b_hid[2 * HH + h], bo = b_hid[3 * HH + h];
    int mbase = mt * 16 + (lane >> 4) * 4;
#pragma unroll
    for (int r = 0; r < 4; ++r) {
        int b = mbase + r;
        const u16* xr = xg_t + (size_t)b * H4;
        float ig = sigmoidf_(a0[r] + bi + bf2f(xr[h]));
        float fg = sigmoidf_(a1[r] + bff + bf2f(xr[HH + h]));
        float gg = fast_tanh(a2[r] + bg + bf2f(xr[2 * HH + h]));
        float og = sigmoidf_(a3[r] + bo + bf2f(xr[3 * HH + h]));
        int ci = b * HH + h;
        float cy = fg * cell[ci] + ig * gg;
        float hy = og * fast_tanh(cy);
        cell[ci] = cy;
        outh_t[(size_t)b * TT * HH + h] = hy;
        hy_out[(size_t)b * H2 + h] = f2bf(hy);
    }
}

// ---------- K2: target = hy @ Wa_in.T ----------
__global__ __launch_bounds__(256) void k_target_gemm(const u16* __restrict__ hybf,
                                                     const u16* __restrict__ wainbf,
                                                     float* __restrict__ target) {
    int lane = threadIdx.x & 63, wave = threadIdx.x >> 6;
    int tile = blockIdx.x * 4 + wave;    // 256 tiles
    int mt = tile >> 6, nt = tile & 63;
    int kq = (lane >> 4) * 8;
    const u16* ap = hybf + (size_t)(mt * 16 + (lane & 15)) * H2 + kq;
    const u16* bp = wainbf + (size_t)(nt * 16 + (lane & 15)) * HH + kq;
    f32x4 acc = {0,0,0,0};
#pragma unroll 4
    for (int k = 0; k < HH; k += 32)
        acc = __builtin_amdgcn_mfma_f32_16x16x32_bf16(*(const short8*)(ap + k),
                                                      *(const short8*)(bp + k), acc, 0, 0, 0);
    int n = nt * 16 + (lane & 15);
    int mbase = mt * 16 + (lane >> 4) * 4;
#pragma unroll
    for (int r = 0; r < 4; ++r)
        target[(size_t)(mbase + r) * HH + n] = acc[r];
}

// ---------- K3: p[b,s] = exp(e[b,s]); sump[b] += p ----------
__global__ __launch_bounds__(256) void k_energy_exp(const float* __restrict__ target,
                                                    const u16* __restrict__ srcbf,
                                                    const float* __restrict__ wav,
                                                    float* __restrict__ pbuf,
                                                    float* __restrict__ sump) {
    int b = blockIdx.x >> 4;
    int chunk = blockIdx.x & 15;
    int lane = threadIdx.x & 63, wave = threadIdx.x >> 6;
    int hb = lane * 16;
    f32x4 tg[4], wv[4];
#pragma unroll
    for (int q = 0; q < 4; ++q) {
        tg[q] = *(const f32x4*)(target + (size_t)b * HH + hb + q * 4);
        wv[q] = *(const f32x4*)(wav + hb + q * 4);
    }
    float psum = 0.f;
    float pv[4];
#pragma unroll
    for (int r = 0; r < 4; ++r) {
        int s = chunk * 16 + wave * 4 + r;
        const u16* sp = srcbf + (size_t)(b * SS + s) * HH + hb;
        short8 s0 = *(const short8*)(sp);
        short8 s1 = *(const short8*)(sp + 8);
        float acc = 0.f;
#pragma unroll
        for (int j = 0; j < 8; ++j)
            acc += fast_tanh(tg[j >> 2][j & 3] + bf2f(((const u16*)&s0)[j])) * wv[j >> 2][j & 3];
#pragma unroll
        for (int j = 0; j < 8; ++j)
            acc += fast_tanh(tg[2 + (j >> 2)][j & 3] + bf2f(((const u16*)&s1)[j])) * wv[2 + (j >> 2)][j & 3];
        for (int m = 32; m >= 1; m >>= 1) acc += __shfl_xor(acc, m);
        float p = fexp2(acc * 1.4426950408889634f);
        pv[r] = p;
        psum += p;
    }
    if (lane == 0) {
        int sb = chunk * 16 + wave * 4;
#pragma unroll
        for (int r = 0; r < 4; ++r) pbuf[b * SS + sb + r] = pv[r];
        atomicAdd(&sump[b], psum);
    }
}

// ---------- K4: context + normalize + attn_out ----------
// grid 64 blocks (one per b) x 1024 thr (16 waves, 4 s-groups x 256 h-groups)
__global__ __launch_bounds__(1024) void k_ctx_norm(const float* __restrict__ pbuf,
                                                   const float* __restrict__ sump,
                                                   const u16* __restrict__ ctxbf,
                                                   float* __restrict__ outc_t,     // out+2BTH+t*HH
                                                   float* __restrict__ outattn_t,  // out+3BTH+t*SS
                                                   u16* __restrict__ cbf_out) {    // buf[t&1] (c half)
    __shared__ f32x4 red[4][256];
    int b = blockIdx.x;
    int tid = threadIdx.x;
    int hq = tid & 255, sg = tid >> 8;
    int h0 = hq * 4;
    float inv = 1.f / sump[b];

    f32x4 acc = {0.f, 0.f, 0.f, 0.f};
    const float* pb = pbuf + b * SS + sg * 64;
    const u16* cp = ctxbf + ((size_t)(b * SS + sg * 64)) * HH + h0;
#pragma unroll 4
    for (int i = 0; i < 64; ++i) {
        float p = pb[i];
        short4v v = *(const short4v*)(cp + (size_t)i * HH);
        acc[0] += p * bf2f(((const u16*)&v)[0]);
        acc[1] += p * bf2f(((const u16*)&v)[1]);
        acc[2] += p * bf2f(((const u16*)&v)[2]);
        acc[3] += p * bf2f(((const u16*)&v)[3]);
    }
    red[sg][hq] = acc;
    if (tid < 256) outattn_t[(size_t)b * TT * SS + tid] = pbuf[b * SS + tid] * inv;
    __syncthreads();
    if (sg == 0) {
        f32x4 t0 = red[0][hq], t1 = red[1][hq], t2 = red[2][hq], t3 = red[3][hq];
        f32x4 c;
#pragma unroll
        for (int j = 0; j < 4; ++j) c[j] = (t0[j] + t1[j] + t2[j] + t3[j]) * inv;
        *(f32x4*)(outc_t + (size_t)b * TT * HH + h0) = c;
        u16x4 pk;
#pragma unroll
        for (int j = 0; j < 4; ++j) pk[j] = f2bf(c[j]);
        *(u16x4*)(cbf_out + (size_t)b * H2 + h0) = pk;
    }
}

// ---------- K5: h_tilde = tanh([c,hy] @ Wa_out.T) ----------
__global__ __launch_bounds__(256) void k_htilde_gemm(const u16* __restrict__ abuf2,
                                                     const u16* __restrict__ waoutbf,
                                                     float* __restrict__ outht_t) {
    int lane = threadIdx.x & 63, wave = threadIdx.x >> 6;
    int tile = blockIdx.x * 4 + wave;    // 256 tiles
    int mt = tile >> 6, nt = tile & 63;
    int kq = (lane >> 4) * 8;
    const u16* ap = abuf2 + (size_t)(mt * 16 + (lane & 15)) * H2 + kq;
    const u16* bp = waoutbf + (size_t)(nt * 16 + (lane & 15)) * H2 + kq;
    f32x4 acc = {0,0,0,0};
#pragma unroll 4
    for (int k = 0; k < H2; k += 32)
        acc = __builtin_amdgcn_mfma_f32_16x16x32_bf16(*(const short8*)(ap + k),
                                                      *(const short8*)(bp + k), acc, 0, 0, 0);
    int n = nt * 16 + (lane & 15);
    int mbase = mt * 16 + (lane >> 4) * 4;
#pragma unroll
    for (int r = 0; r < 4; ++r)
        outht_t[(size_t)(mbase + r) * TT * HH + n] = fast_tanh(acc[r]);
}

__global__ __launch_bounds__(256) void k_final(const float* __restrict__ cell,
                                               float* __restrict__ out) {
    int i = blockIdx.x * 256 + threadIdx.x;  // B*H
    int b = i >> 10, h = i & 1023;
    size_t hy_off = 3 * BTH + BTS;
    out[hy_off + i] = out[(size_t)b * TT * HH + (size_t)(TT - 1) * HH + h];
    out[hy_off + (size_t)BB * HH + i] = cell[i];
}

extern "C" void kernel_launch(void* const* d_in, const int* in_sizes, int n_in,
                              void* d_out, int out_size, void* d_ws, size_t ws_size,
                              hipStream_t stream) {
    const float* input  = (const float*)d_in[0];
    const float* hx0    = (const float*)d_in[1];
    const float* cx0    = (const float*)d_in[2];
    const float* ctx    = (const float*)d_in[3];
    const float* W_in   = (const float*)d_in[4];
    const float* b_in   = (const float*)d_in[5];
    const float* W_hid  = (const float*)d_in[6];
    const float* b_hid  = (const float*)d_in[7];
    const float* Wa_in  = (const float*)d_in[8];
    const float* Wa_c   = (const float*)d_in[9];
    const float* ba_c   = (const float*)d_in[10];
    const float* Wa_v   = (const float*)d_in[11];
    const float* Wa_out = (const float*)d_in[12];
    float* out = (float*)d_out;
    (void)in_sizes; (void)n_in; (void)out_size; (void)ws_size;

    char* w = (char*)d_ws;
    size_t off = 0;
    auto take = [&](size_t bytes) -> void* {
        void* p = w + off;
        off += (bytes + 255) & ~(size_t)255;
        return p;
    };
    u16* xg      = (u16*)take((size_t)TT * BB * H4 * 2);   // 128 MB, rows m=t*64+b
    u16* srcbf   = (u16*)take((size_t)BB * SS * HH * 2);   // 32 MB
    u16* ctxbf   = (u16*)take((size_t)BB * SS * HH * 2);   // 32 MB
    u16* inbf    = (u16*)take((size_t)BB * TT * II * 2);   // 32 MB, time-major
    u16* winbf   = (u16*)take((size_t)H4 * II * 2);
    u16* whidbf  = (u16*)take((size_t)H4 * HH * 2);
    u16* wainbf  = (u16*)take((size_t)HH * HH * 2);
    u16* wacbf   = (u16*)take((size_t)HH * HH * 2);
    u16* waoutbf = (u16*)take((size_t)HH * H2 * 2);
    float* target = (float*)take((size_t)BB * HH * 4);
    float* pbuf   = (float*)take((size_t)BB * SS * 4);
    float* sump   = (float*)take((size_t)BB * 4);
    float* cell   = (float*)take((size_t)BB * HH * 4);
    u16* buf0     = (u16*)take((size_t)BB * H2 * 2);       // [c | hy] bf16
    u16* buf1     = (u16*)take((size_t)BB * H2 * 2);

    // one-time precompute
    k_f2bf_tm<<<(BB * TT * II) / 256, 256, 0, stream>>>(input, inbf);
    k_f2bf<<<(H4 * II) / 256, 256, 0, stream>>>(W_in, winbf, H4 * II);
    k_f2bf<<<(H4 * HH) / 256, 256, 0, stream>>>(W_hid, whidbf, H4 * HH);
    k_f2bf<<<(HH * HH) / 256, 256, 0, stream>>>(Wa_in, wainbf, HH * HH);
    k_f2bf<<<(HH * HH) / 256, 256, 0, stream>>>(Wa_c, wacbf, HH * HH);
    k_f2bf<<<(HH * H2) / 256, 256, 0, stream>>>(Wa_out, waoutbf, HH * H2);
    k_f2bf<<<(BB * SS * HH) / 256, 256, 0, stream>>>(ctx, ctxbf, BB * SS * HH);

    // xg[t*64+b, :] = input_tm @ W_in.T + b_in   (M=16384, N=4096, K=1024)
    k_gemm128<<<dim3(H4 / 128, (TT * BB) / 128), 256, 0, stream>>>(inbf, winbf, b_in, xg, H4, II);
    // source[b*S+s, :] = ctx @ Wa_c.T + ba_c     (M=16384, N=1024, K=1024)
    k_gemm128<<<dim3(HH / 128, (BB * SS) / 128), 256, 0, stream>>>(ctxbf, wacbf, ba_c, srcbf, HH, HH);
    k_init<<<256, 256, 0, stream>>>(hx0, cx0, cell, buf1);

    for (int t = 0; t < TT; ++t) {
        u16* cur  = (t & 1) ? buf1 : buf0;
        u16* prev = (t & 1) ? buf0 : buf1;
        k_gates_cell<<<256, 64, 0, stream>>>(prev + HH, whidbf, xg + (size_t)t * BB * H4,
                                             b_hid, cell, out + (size_t)t * HH,
                                             cur + HH, sump);
        k_target_gemm<<<64, 256, 0, stream>>>(cur + HH, wainbf, target);
        k_energy_exp<<<1024, 256, 0, stream>>>(target, srcbf, Wa_v, pbuf, sump);
        k_ctx_norm<<<64, 1024, 0, stream>>>(pbuf, sump, ctxbf,
                                            out + 2 * BTH + (size_t)t * HH,
                                            out + 3 * BTH + (size_t)t * SS, cur);
        k_htilde_gemm<<<64, 256, 0, stream>>>(cur, waoutbf, out + BTH + (size_t)t * HH);
    }
    k_final<<<256, 256, 0, stream>>>(cell, out);
}